// Round 1
// baseline (1365.111 us; speedup 1.0000x reference)
//
#include <hip/hip_runtime.h>
#include <math.h>

#define EPS_N 1e-12f
#define MARGIN 0.3f
#define INF_BITS 0x7f800000u

// ---------------------------------------------------------------------------
// K1: row-wise L2 normalize; also emit sq[i] = ||f_i||^2 (post-normalization).
// One block (256 thr) per row.
// ---------------------------------------------------------------------------
__global__ void k_normalize(const float* __restrict__ x, float* __restrict__ fn,
                            float* __restrict__ sq, int Dx) {
    int row = blockIdx.x;
    const float* xr = x + (size_t)row * Dx;
    float ss = 0.f;
    for (int c = threadIdx.x; c < Dx; c += blockDim.x) { float v = xr[c]; ss = fmaf(v, v, ss); }
    int lane = threadIdx.x & 63, wid = threadIdx.x >> 6;
    #pragma unroll
    for (int off = 32; off; off >>= 1) ss += __shfl_down(ss, off, 64);
    __shared__ float warp_s[4];
    __shared__ float inv_s;
    if (lane == 0) warp_s[wid] = ss;
    __syncthreads();
    if (threadIdx.x == 0) {
        float t = warp_s[0] + warp_s[1] + warp_s[2] + warp_s[3];
        float norm = sqrtf(t);
        float inv = 1.0f / fmaxf(norm, EPS_N);
        inv_s = inv;
        sq[row] = t * inv * inv;
    }
    __syncthreads();
    float inv = inv_s;
    float* fr = fn + (size_t)row * Dx;
    for (int c = threadIdx.x; c < Dx; c += blockDim.x) fr[c] = xr[c] * inv;
}

// ---------------------------------------------------------------------------
// K2: per-anchor positive stats. One block per anchor: build same-label list
// in LDS, then one wave per match computes the dot / distance.
// Also initializes minbits[i] = +inf for K3.
// ---------------------------------------------------------------------------
__global__ void k_posstats(const float* __restrict__ fn, const int* __restrict__ lab,
                           const float* __restrict__ sq,
                           float* __restrict__ meanpos, int* __restrict__ poscnt,
                           unsigned* __restrict__ minbits, int Bn, int Dx) {
    __shared__ float fi[512];
    __shared__ int mlist[8192];
    __shared__ int nm;
    __shared__ float wsum[4];
    int i = blockIdx.x;
    int tid = threadIdx.x;
    if (tid == 0) nm = 0;
    if (tid < 4) wsum[tid] = 0.f;
    for (int c = tid; c < Dx; c += 256) fi[c] = fn[(size_t)i * Dx + c];
    __syncthreads();
    int li = lab[i];
    for (int j = tid; j < Bn; j += 256) {
        if (lab[j] == li) { int p = atomicAdd(&nm, 1); if (p < 8192) mlist[p] = j; }
    }
    __syncthreads();
    int cnt = nm;
    float sqi = sq[i];
    int lane = tid & 63, wid = tid >> 6;
    for (int m = wid; m < cnt; m += 4) {
        int j = mlist[m];
        const float* fj = fn + (size_t)j * Dx;
        float dot = 0.f;
        for (int c = lane; c < Dx; c += 64) dot = fmaf(fi[c], fj[c], dot);
        #pragma unroll
        for (int off = 32; off; off >>= 1) dot += __shfl_down(dot, off, 64);
        if (lane == 0) {
            float d2 = sqi + sq[j] - 2.0f * dot;
            float dist = (d2 > 0.f) ? sqrtf(d2) : 0.f;
            wsum[wid] += dist;   // one lane per wave: race-free, serialized
        }
    }
    __syncthreads();
    if (tid == 0) {
        float s = wsum[0] + wsum[1] + wsum[2] + wsum[3];
        meanpos[i] = s / (float)cnt;   // cnt >= 1 (self always matches)
        poscnt[i] = cnt;
        minbits[i] = INF_BITS;
    }
}

// ---------------------------------------------------------------------------
// K3: fused 8192x8192x512 fp32 GEMM + semi-hard row-min.
// 128x128 tile / block, 256 threads, 8x8 micro-tile, BK=16.
// dist(i,j) = sqrt(max(sq_i + sq_j - 2*dot, 0)); eligible if labels differ
// and dist > mean_pos_i. Row-min via 16-lane shfl_xor then global atomicMin
// on float bits (valid: distances are non-negative).
// ---------------------------------------------------------------------------
#define BM 128
#define BN 128
#define BK 16
#define LDT 132  // +4 pad: staging writes 2-way bank-aliased (free), b128 reads stay 16B-aligned

__global__ __launch_bounds__(256) void k_minsh(
    const float* __restrict__ fn, const float* __restrict__ sq,
    const int* __restrict__ lab, const float* __restrict__ meanpos,
    unsigned* __restrict__ minbits, int Bn, int Dx)
{
    __shared__ float As[BK][LDT];
    __shared__ float Bs[BK][LDT];
    __shared__ float s_mpos[BM], s_sqr[BM], s_sqc[BN];
    __shared__ int s_labr[BM], s_labc[BN];

    int i0 = blockIdx.y * BM;
    int j0 = blockIdx.x * BN;
    int tid = threadIdx.x;
    int tx = tid & 15, ty = tid >> 4;

    if (tid < BM) {
        s_mpos[tid] = meanpos[i0 + tid];
        s_sqr[tid]  = sq[i0 + tid];
        s_labr[tid] = lab[i0 + tid];
    } else {
        int t = tid - BM;
        s_sqc[t]  = sq[j0 + t];
        s_labc[t] = lab[j0 + t];
    }

    float acc[8][8] = {};
    const float* Aop = fn + (size_t)i0 * Dx;
    const float* Bop = fn + (size_t)j0 * Dx;

    int r  = tid >> 2;          // 0..63
    int kv = (tid & 3) * 4;     // 0,4,8,12

    for (int k0 = 0; k0 < Dx; k0 += BK) {
        __syncthreads();  // protect LDS from readers of previous iter / metadata writers
        #pragma unroll
        for (int h = 0; h < 2; ++h) {
            int row = r + h * 64;
            float4 a = *(const float4*)(Aop + (size_t)row * Dx + k0 + kv);
            As[kv + 0][row] = a.x; As[kv + 1][row] = a.y;
            As[kv + 2][row] = a.z; As[kv + 3][row] = a.w;
            float4 b = *(const float4*)(Bop + (size_t)row * Dx + k0 + kv);
            Bs[kv + 0][row] = b.x; Bs[kv + 1][row] = b.y;
            Bs[kv + 2][row] = b.z; Bs[kv + 3][row] = b.w;
        }
        __syncthreads();
        #pragma unroll
        for (int kk = 0; kk < BK; ++kk) {
            float a[8], b[8];
            *(float4*)&a[0] = *(const float4*)&As[kk][ty * 8];
            *(float4*)&a[4] = *(const float4*)&As[kk][ty * 8 + 4];
            *(float4*)&b[0] = *(const float4*)&Bs[kk][tx * 8];
            *(float4*)&b[4] = *(const float4*)&Bs[kk][tx * 8 + 4];
            #pragma unroll
            for (int m = 0; m < 8; ++m)
                #pragma unroll
                for (int n = 0; n < 8; ++n)
                    acc[m][n] = fmaf(a[m], b[n], acc[m][n]);
        }
    }
    __syncthreads();

    // Epilogue: distance + mask + row-min
    #pragma unroll
    for (int m = 0; m < 8; ++m) {
        int   li = s_labr[ty * 8 + m];
        float mp = s_mpos[ty * 8 + m];
        float sr = s_sqr[ty * 8 + m];
        float vmin = __uint_as_float(INF_BITS);
        #pragma unroll
        for (int n = 0; n < 8; ++n) {
            float d2 = sr + s_sqc[tx * 8 + n] - 2.0f * acc[m][n];
            float dist = (d2 > 0.f) ? sqrtf(d2) : 0.f;
            bool ok = (li != s_labc[tx * 8 + n]) && (dist > mp);
            vmin = ok ? fminf(vmin, dist) : vmin;
        }
        // rows are owned by 16 consecutive lanes (same ty, tx 0..15) in one wave
        #pragma unroll
        for (int off = 8; off; off >>= 1)
            vmin = fminf(vmin, __shfl_xor(vmin, off, 64));
        if (tx == 0 && __float_as_uint(vmin) != INF_BITS)
            atomicMin(&minbits[i0 + ty * 8 + m], __float_as_uint(vmin));
    }
}

// ---------------------------------------------------------------------------
// K4: final scalar reduction over anchors.
// ---------------------------------------------------------------------------
__global__ void k_finish(const float* __restrict__ meanpos, const int* __restrict__ poscnt,
                         const unsigned* __restrict__ minbits, float* __restrict__ out, int Bn) {
    float lsum = 0.f; int lcnt = 0;
    for (int i = threadIdx.x; i < Bn; i += blockDim.x) {
        int pc = poscnt[i];
        bool valid = (pc > 1) && (pc < Bn);
        unsigned mb = minbits[i];
        bool has_sh = (mb != INF_BITS);
        if (valid && has_sh) {
            float v = meanpos[i] - __uint_as_float(mb) + MARGIN;
            lsum += (v > 0.f) ? v : 0.f;
            lcnt += 1;
        }
    }
    __shared__ float ssum[4]; __shared__ int scnt[4];
    int lane = threadIdx.x & 63, wid = threadIdx.x >> 6;
    #pragma unroll
    for (int off = 32; off; off >>= 1) {
        lsum += __shfl_down(lsum, off, 64);
        lcnt += __shfl_down(lcnt, off, 64);
    }
    if (lane == 0) { ssum[wid] = lsum; scnt[wid] = lcnt; }
    __syncthreads();
    if (threadIdx.x == 0) {
        float s = ssum[0] + ssum[1] + ssum[2] + ssum[3];
        int   c = scnt[0] + scnt[1] + scnt[2] + scnt[3];
        out[0] = (c > 0) ? s / (float)c : 0.f;
    }
}

// ---------------------------------------------------------------------------
extern "C" void kernel_launch(void* const* d_in, const int* in_sizes, int n_in,
                              void* d_out, int out_size, void* d_ws, size_t ws_size,
                              hipStream_t stream) {
    const float* x  = (const float*)d_in[0];
    const int* lab  = (const int*)d_in[1];
    int Bn = in_sizes[1];
    int Dx = in_sizes[0] / Bn;

    char* ws = (char*)d_ws;
    float*    fnp     = (float*)ws;                                   // B*D
    float*    sqp     = (float*)(ws + (size_t)Bn * Dx * sizeof(float)); // B
    float*    meanpos = sqp + Bn;                                     // B
    int*      poscnt  = (int*)(meanpos + Bn);                         // B
    unsigned* minbits = (unsigned*)(poscnt + Bn);                     // B

    k_normalize<<<Bn, 256, 0, stream>>>(x, fnp, sqp, Dx);
    k_posstats<<<Bn, 256, 0, stream>>>(fnp, lab, sqp, meanpos, poscnt, minbits, Bn, Dx);
    dim3 grid(Bn / BN, Bn / BM);
    k_minsh<<<grid, 256, 0, stream>>>(fnp, sqp, lab, meanpos, minbits, Bn, Dx);
    k_finish<<<1, 256, 0, stream>>>(meanpos, poscnt, minbits, (float*)d_out, Bn);
}

// Round 2
// 612.459 us; speedup vs baseline: 2.2289x; 2.2289x over previous
//
#include <hip/hip_runtime.h>
#include <math.h>

#define EPS_N 1e-12f
#define MARGIN 0.3f
#define INF_BITS 0x7f800000u
#define NC 8192      // class-id space (labels are 0..127; clamped into this)
#define MAXM 256     // max class size on the fast path
#define D 512

typedef __attribute__((ext_vector_type(8))) short short8;   // 8 bf16 = 4 VGPRs
typedef __attribute__((ext_vector_type(4))) float float4v;  // MFMA 16x16 accum

__device__ __forceinline__ unsigned short f2bf(float f) {   // RNE bf16
    unsigned u = __float_as_uint(f);
    u += 0x7fff + ((u >> 16) & 1);
    return (unsigned short)(u >> 16);
}
__device__ __forceinline__ float bf2f(unsigned short h) {
    return __uint_as_float(((unsigned)h) << 16);
}
__device__ __forceinline__ void gl16(const void* g, void* l) {
    // 16B-wide async global->LDS; LDS dest is wave-uniform base + lane*16
    __builtin_amdgcn_global_load_lds((const __attribute__((address_space(1))) void*)g,
                                     (__attribute__((address_space(3))) void*)l, 16, 0, 0);
}

// ---------------------------------------------------------------------------
// K1: normalize rows; emit bf16 hi/lo split (a ~= hi + lo, err ~2^-16) + sq.
// ---------------------------------------------------------------------------
__global__ void k_normalize(const float* __restrict__ x, unsigned short* __restrict__ fh,
                            unsigned short* __restrict__ fl, float* __restrict__ sq) {
    int row = blockIdx.x;
    const float* xr = x + (size_t)row * D;
    float ss = 0.f;
    for (int c = threadIdx.x; c < D; c += 256) { float v = xr[c]; ss = fmaf(v, v, ss); }
    int lane = threadIdx.x & 63, wid = threadIdx.x >> 6;
    #pragma unroll
    for (int off = 32; off; off >>= 1) ss += __shfl_down(ss, off, 64);
    __shared__ float warp_s[4];
    __shared__ float inv_s;
    if (lane == 0) warp_s[wid] = ss;
    __syncthreads();
    if (threadIdx.x == 0) {
        float t = warp_s[0] + warp_s[1] + warp_s[2] + warp_s[3];
        float inv = 1.0f / fmaxf(sqrtf(t), EPS_N);
        inv_s = inv;
        sq[row] = t * inv * inv;
    }
    __syncthreads();
    float inv = inv_s;
    for (int c = threadIdx.x; c < D; c += 256) {
        float a = xr[c] * inv;
        unsigned short h = f2bf(a);
        fh[(size_t)row * D + c] = h;
        fl[(size_t)row * D + c] = f2bf(a - bf2f(h));
    }
}

// ---------------------------------------------------------------------------
// Class bucketing: zero -> count -> scan -> scatter
// ---------------------------------------------------------------------------
__global__ void k_zero(int* __restrict__ ccnt, int* __restrict__ coff) {
    int i = blockIdx.x * 256 + threadIdx.x;
    if (i < NC) { ccnt[i] = 0; coff[i] = 0; }
}
__global__ void k_count(const int* __restrict__ lab, int* __restrict__ ccnt, int Bn) {
    for (int j = blockIdx.x * 256 + threadIdx.x; j < Bn; j += gridDim.x * 256)
        atomicAdd(&ccnt[lab[j] & (NC - 1)], 1);
}
__global__ void k_scan(const int* __restrict__ ccnt, int* __restrict__ cstart) {
    __shared__ int part[256];
    int t = threadIdx.x;
    int s = 0;
    for (int c = t * 32; c < t * 32 + 32; ++c) s += ccnt[c];
    part[t] = s;
    __syncthreads();
    if (t == 0) { int run = 0; for (int q = 0; q < 256; ++q) { int v = part[q]; part[q] = run; run += v; } }
    __syncthreads();
    int run = part[t];
    for (int c = t * 32; c < t * 32 + 32; ++c) { cstart[c] = run; run += ccnt[c]; }
}
__global__ void k_scatter(const int* __restrict__ lab, const int* __restrict__ cstart,
                          int* __restrict__ coff, int* __restrict__ cmember, int Bn) {
    for (int j = blockIdx.x * 256 + threadIdx.x; j < Bn; j += gridDim.x * 256) {
        int l = lab[j] & (NC - 1);
        int p = atomicAdd(&coff[l], 1);
        cmember[cstart[l] + p] = j;
    }
}

// ---------------------------------------------------------------------------
// K2: per-class positive stats. One block per class, 4x4 register pair-tiles.
// Also writes poscnt and inits minbits = +inf for every anchor.
// ---------------------------------------------------------------------------
__global__ void k_posstats2(const unsigned short* __restrict__ fh, const unsigned short* __restrict__ fl,
                            const float* __restrict__ sq,
                            const int* __restrict__ cmember, const int* __restrict__ cstart,
                            const int* __restrict__ ccnt,
                            float* __restrict__ meanpos, int* __restrict__ poscnt,
                            unsigned* __restrict__ minbits) {
    __shared__ int ml[MAXM];
    __shared__ float rs[MAXM];
    int c = blockIdx.x;
    int m = ccnt[c];
    if (m == 0) return;
    int st = cstart[c];
    int tid = threadIdx.x;

    if (m <= MAXM) {
        for (int t = tid; t < m; t += 256) { ml[t] = cmember[st + t]; rs[t] = 0.f; }
        __syncthreads();
        int nb = (m + 3) >> 2;
        int tiles = nb * nb;
        for (int p = tid; p < tiles; p += 256) {
            int ta = (p / nb) * 4, tb = (p % nb) * 4;
            int ga[4], gb[4];
            #pragma unroll
            for (int i = 0; i < 4; ++i) {
                ga[i] = ml[min(ta + i, m - 1)];
                gb[i] = ml[min(tb + i, m - 1)];
            }
            float dot[4][4] = {};
            for (int k = 0; k < D; k += 4) {
                float av[4][4], bv[4][4];
                #pragma unroll
                for (int i = 0; i < 4; ++i) {
                    ushort4 h  = *(const ushort4*)(fh + (size_t)ga[i] * D + k);
                    ushort4 lo = *(const ushort4*)(fl + (size_t)ga[i] * D + k);
                    av[i][0] = bf2f(h.x) + bf2f(lo.x); av[i][1] = bf2f(h.y) + bf2f(lo.y);
                    av[i][2] = bf2f(h.z) + bf2f(lo.z); av[i][3] = bf2f(h.w) + bf2f(lo.w);
                    ushort4 hb = *(const ushort4*)(fh + (size_t)gb[i] * D + k);
                    ushort4 lb = *(const ushort4*)(fl + (size_t)gb[i] * D + k);
                    bv[i][0] = bf2f(hb.x) + bf2f(lb.x); bv[i][1] = bf2f(hb.y) + bf2f(lb.y);
                    bv[i][2] = bf2f(hb.z) + bf2f(lb.z); bv[i][3] = bf2f(hb.w) + bf2f(lb.w);
                }
                #pragma unroll
                for (int i = 0; i < 4; ++i) {
                    #pragma unroll
                    for (int j = 0; j < 4; ++j) {
                        #pragma unroll
                        for (int kk = 0; kk < 4; ++kk)
                            dot[i][j] = fmaf(av[i][kk], bv[j][kk], dot[i][j]);
                    }
                }
            }
            #pragma unroll
            for (int i = 0; i < 4; ++i) {
                if (ta + i < m) {
                    float rsum = 0.f;
                    #pragma unroll
                    for (int j = 0; j < 4; ++j) {
                        if (tb + j < m) {
                            float d2 = sq[ga[i]] + sq[gb[j]] - 2.0f * dot[i][j];
                            rsum += (d2 > 0.f) ? sqrtf(d2) : 0.f;
                        }
                    }
                    atomicAdd(&rs[ta + i], rsum);
                }
            }
        }
        __syncthreads();
        for (int t = tid; t < m; t += 256) {
            int g = ml[t];
            meanpos[g] = rs[t] / (float)m;
            poscnt[g] = m;
            minbits[g] = INF_BITS;
        }
    } else {
        // slow-but-correct fallback for pathological class sizes (never hit here)
        for (int t = tid; t < m; t += 256) meanpos[cmember[st + t]] = 0.f;
        __syncthreads();
        for (size_t p = tid; p < (size_t)m * m; p += 256) {
            int a = (int)(p / m), b = (int)(p % m);
            int ga = cmember[st + a], gb = cmember[st + b];
            float dotv = 0.f;
            for (int k = 0; k < D; ++k)
                dotv = fmaf(bf2f(fh[(size_t)ga * D + k]) + bf2f(fl[(size_t)ga * D + k]),
                            bf2f(fh[(size_t)gb * D + k]) + bf2f(fl[(size_t)gb * D + k]), dotv);
            float d2 = sq[ga] + sq[gb] - 2.0f * dotv;
            atomicAdd(&meanpos[ga], (d2 > 0.f) ? sqrtf(d2) : 0.f);
        }
        __syncthreads();
        for (int t = tid; t < m; t += 256) {
            int g = cmember[st + t];
            meanpos[g] /= (float)m;
            poscnt[g] = m;
            minbits[g] = INF_BITS;
        }
    }
}

// ---------------------------------------------------------------------------
// K3: bf16-split MFMA GEMM (hi*hi + hi*lo + lo*hi) + fused semi-hard row-min.
// 128x128 tile, 256 thr = 4 waves, each wave 4x4 of 16x16x32 MFMA tiles.
// Staging via global_load_lds(16B) with XOR seg-swizzle so fragment
// ds_read_b128s are 2-way bank-aliased (free).
// ---------------------------------------------------------------------------
__global__ __launch_bounds__(256, 2) void k_minsh_mfma(
    const unsigned short* __restrict__ fh, const unsigned short* __restrict__ fl,
    const float* __restrict__ sq, const int* __restrict__ lab,
    const float* __restrict__ meanpos, unsigned* __restrict__ minbits)
{
    // LA[0]=A_hi, LA[1]=A_lo, LA[2]=B_hi, LA[3]=B_lo; each 128 rows x 32 bf16
    __shared__ unsigned short LA[4][4096];
    __shared__ float s_mpos[128], s_sqr[128], s_sqc[128];
    __shared__ int s_labr[128], s_labc[128];

    const int i0 = blockIdx.y * 128, j0 = blockIdx.x * 128;
    const int tid = threadIdx.x;
    const int w = tid >> 6, L = tid & 63;

    if (tid < 128) {
        s_mpos[tid] = meanpos[i0 + tid];
        s_sqr[tid]  = sq[i0 + tid];
        s_labr[tid] = lab[i0 + tid];
    } else {
        int t = tid - 128;
        s_sqc[t]  = sq[j0 + t];
        s_labc[t] = lab[j0 + t];
    }

    const unsigned short* msrc = (w & 1) ? fl : fh;   // wave stages one matrix
    const int rbase = (w < 2) ? i0 : j0;
    unsigned short* mylds = &LA[w][0];
    const int srow = L >> 2;       // row offset within a 16-row group
    const int sseg = L & 3;        // LDS slot seg for this lane

    float4v acc[4][4];
    #pragma unroll
    for (int a = 0; a < 4; ++a) {
        #pragma unroll
        for (int b = 0; b < 4; ++b) acc[a][b] = (float4v){0.f, 0.f, 0.f, 0.f};
    }

    const int rw = (w >> 1) * 64, cw = (w & 1) * 64;
    const int lm = L & 15, ls = L >> 4;

    for (int k0 = 0; k0 < D; k0 += 32) {
        __syncthreads();
        #pragma unroll
        for (int it = 0; it < 8; ++it) {
            int r = it * 16 + srow;
            int seg = sseg ^ ((r >> 1) & 3);     // source seg for this LDS slot
            const unsigned short* g = msrc + (size_t)(rbase + r) * D + k0 + seg * 8;
            gl16(g, mylds + it * 512);           // lds ptr wave-uniform; +L*16B implied
        }
        __syncthreads();

        short8 ah[4], al[4];
        #pragma unroll
        for (int mi = 0; mi < 4; ++mi) {
            int r = rw + mi * 16 + lm;
            int slot = r * 4 + (ls ^ ((r >> 1) & 3));
            ah[mi] = *(const short8*)&LA[0][slot * 8];
            al[mi] = *(const short8*)&LA[1][slot * 8];
        }
        #pragma unroll
        for (int ni = 0; ni < 4; ++ni) {
            int c = cw + ni * 16 + lm;
            int slot = c * 4 + (ls ^ ((c >> 1) & 3));
            short8 bh = *(const short8*)&LA[2][slot * 8];
            short8 bl = *(const short8*)&LA[3][slot * 8];
            #pragma unroll
            for (int mi = 0; mi < 4; ++mi) {
                acc[mi][ni] = __builtin_amdgcn_mfma_f32_16x16x32_bf16(ah[mi], bh, acc[mi][ni], 0, 0, 0);
                acc[mi][ni] = __builtin_amdgcn_mfma_f32_16x16x32_bf16(ah[mi], bl, acc[mi][ni], 0, 0, 0);
                acc[mi][ni] = __builtin_amdgcn_mfma_f32_16x16x32_bf16(al[mi], bh, acc[mi][ni], 0, 0, 0);
            }
        }
    }

    // Epilogue: C/D layout col=lane&15, row=(lane>>4)*4+reg [m89-verified]
    #pragma unroll
    for (int mi = 0; mi < 4; ++mi) {
        #pragma unroll
        for (int v = 0; v < 4; ++v) {
            int rl = rw + mi * 16 + ls * 4 + v;
            float mp = s_mpos[rl];
            float sr = s_sqr[rl];
            int   li = s_labr[rl];
            float vmin = __uint_as_float(INF_BITS);
            #pragma unroll
            for (int ni = 0; ni < 4; ++ni) {
                int cl = cw + ni * 16 + lm;
                float d2 = sr + s_sqc[cl] - 2.0f * acc[mi][ni][v];
                float dist = (d2 > 0.f) ? sqrtf(d2) : 0.f;
                bool ok = (li != s_labc[cl]) && (dist > mp);
                vmin = ok ? fminf(vmin, dist) : vmin;
            }
            #pragma unroll
            for (int off = 8; off; off >>= 1)
                vmin = fminf(vmin, __shfl_xor(vmin, off, 64));
            if (lm == 0 && __float_as_uint(vmin) != INF_BITS)
                atomicMin(&minbits[i0 + rl], __float_as_uint(vmin));
        }
    }
}

// ---------------------------------------------------------------------------
// K4: final scalar reduction.
// ---------------------------------------------------------------------------
__global__ void k_finish(const float* __restrict__ meanpos, const int* __restrict__ poscnt,
                         const unsigned* __restrict__ minbits, float* __restrict__ out, int Bn) {
    float lsum = 0.f; int lcnt = 0;
    for (int i = threadIdx.x; i < Bn; i += blockDim.x) {
        int pc = poscnt[i];
        bool valid = (pc > 1) && (pc < Bn);
        unsigned mb = minbits[i];
        if (valid && mb != INF_BITS) {
            float v = meanpos[i] - __uint_as_float(mb) + MARGIN;
            lsum += (v > 0.f) ? v : 0.f;
            lcnt += 1;
        }
    }
    __shared__ float ssum[4]; __shared__ int scnt[4];
    int lane = threadIdx.x & 63, wid = threadIdx.x >> 6;
    #pragma unroll
    for (int off = 32; off; off >>= 1) {
        lsum += __shfl_down(lsum, off, 64);
        lcnt += __shfl_down(lcnt, off, 64);
    }
    if (lane == 0) { ssum[wid] = lsum; scnt[wid] = lcnt; }
    __syncthreads();
    if (threadIdx.x == 0) {
        float s = ssum[0] + ssum[1] + ssum[2] + ssum[3];
        int   c = scnt[0] + scnt[1] + scnt[2] + scnt[3];
        out[0] = (c > 0) ? s / (float)c : 0.f;
    }
}

// ---------------------------------------------------------------------------
extern "C" void kernel_launch(void* const* d_in, const int* in_sizes, int n_in,
                              void* d_out, int out_size, void* d_ws, size_t ws_size,
                              hipStream_t stream) {
    const float* x = (const float*)d_in[0];
    const int* lab = (const int*)d_in[1];
    int Bn = in_sizes[1];                 // 8192; D fixed at 512

    size_t nd = (size_t)Bn * D;
    unsigned short* fh = (unsigned short*)d_ws;
    unsigned short* fl = fh + nd;
    float* sq       = (float*)(fl + nd);
    float* meanpos  = sq + Bn;
    int* poscnt     = (int*)(meanpos + Bn);
    unsigned* minbits = (unsigned*)(poscnt + Bn);
    int* ccnt    = (int*)(minbits + Bn);
    int* cstart  = ccnt + NC;
    int* coff    = cstart + NC;
    int* cmember = coff + NC;

    k_normalize<<<Bn, 256, 0, stream>>>(x, fh, fl, sq);
    k_zero<<<NC / 256, 256, 0, stream>>>(ccnt, coff);
    k_count<<<32, 256, 0, stream>>>(lab, ccnt, Bn);
    k_scan<<<1, 256, 0, stream>>>(ccnt, cstart);
    k_scatter<<<32, 256, 0, stream>>>(lab, cstart, coff, cmember, Bn);
    k_posstats2<<<NC, 256, 0, stream>>>(fh, fl, sq, cmember, cstart, ccnt,
                                        meanpos, poscnt, minbits);
    dim3 grid(Bn / 128, Bn / 128);
    k_minsh_mfma<<<grid, 256, 0, stream>>>(fh, fl, sq, lab, meanpos, minbits);
    k_finish<<<1, 256, 0, stream>>>(meanpos, poscnt, minbits, (float*)d_out, Bn);
}

// Round 3
// 380.100 us; speedup vs baseline: 3.5915x; 1.6113x over previous
//
#include <hip/hip_runtime.h>
#include <math.h>

#define EPS_N 1e-12f
#define MARGIN 0.3f
#define INF_BITS 0x7f800000u
#define NC 8192      // class-id space (labels are 0..127)
#define D 512

typedef __attribute__((ext_vector_type(8))) short short8;   // 8 bf16 = 4 VGPRs
typedef __attribute__((ext_vector_type(4))) float float4v;  // MFMA 16x16 accum

__device__ __forceinline__ unsigned short f2bf(float f) {   // RNE bf16
    unsigned u = __float_as_uint(f);
    u += 0x7fff + ((u >> 16) & 1);
    return (unsigned short)(u >> 16);
}
__device__ __forceinline__ float bf2f(unsigned short h) {
    return __uint_as_float(((unsigned)h) << 16);
}
__device__ __forceinline__ void gl16(const void* g, void* l) {
    // 16B-wide async global->LDS; LDS dest is wave-uniform base + lane*16
    __builtin_amdgcn_global_load_lds((const __attribute__((address_space(1))) void*)g,
                                     (__attribute__((address_space(3))) void*)l, 16, 0, 0);
}

// ---------------------------------------------------------------------------
// K1: normalize rows; emit bf16 hi/lo split (a ~= hi + lo, err ~2^-16) + sq.
// ---------------------------------------------------------------------------
__global__ void k_normalize(const float* __restrict__ x, unsigned short* __restrict__ fh,
                            unsigned short* __restrict__ fl, float* __restrict__ sq) {
    int row = blockIdx.x;
    const float* xr = x + (size_t)row * D;
    float ss = 0.f;
    for (int c = threadIdx.x; c < D; c += 256) { float v = xr[c]; ss = fmaf(v, v, ss); }
    int lane = threadIdx.x & 63, wid = threadIdx.x >> 6;
    #pragma unroll
    for (int off = 32; off; off >>= 1) ss += __shfl_down(ss, off, 64);
    __shared__ float warp_s[4];
    __shared__ float inv_s;
    if (lane == 0) warp_s[wid] = ss;
    __syncthreads();
    if (threadIdx.x == 0) {
        float t = warp_s[0] + warp_s[1] + warp_s[2] + warp_s[3];
        float inv = 1.0f / fmaxf(sqrtf(t), EPS_N);
        inv_s = inv;
        sq[row] = t * inv * inv;
    }
    __syncthreads();
    float inv = inv_s;
    for (int c = threadIdx.x; c < D; c += 256) {
        float a = xr[c] * inv;
        unsigned short h = f2bf(a);
        fh[(size_t)row * D + c] = h;
        fl[(size_t)row * D + c] = f2bf(a - bf2f(h));
    }
}

// ---------------------------------------------------------------------------
// Class bucketing: zero -> count -> scan -> scatter
// ---------------------------------------------------------------------------
__global__ void k_zero(int* __restrict__ ccnt, int* __restrict__ coff) {
    int i = blockIdx.x * 256 + threadIdx.x;
    if (i < NC) { ccnt[i] = 0; coff[i] = 0; }
}
__global__ void k_count(const int* __restrict__ lab, int* __restrict__ ccnt, int Bn) {
    for (int j = blockIdx.x * 256 + threadIdx.x; j < Bn; j += gridDim.x * 256)
        atomicAdd(&ccnt[lab[j] & (NC - 1)], 1);
}
__global__ void k_scan(const int* __restrict__ ccnt, int* __restrict__ cstart) {
    __shared__ int part[256];
    int t = threadIdx.x;
    int s = 0;
    for (int c = t * 32; c < t * 32 + 32; ++c) s += ccnt[c];
    part[t] = s;
    __syncthreads();
    if (t == 0) { int run = 0; for (int q = 0; q < 256; ++q) { int v = part[q]; part[q] = run; run += v; } }
    __syncthreads();
    int run = part[t];
    for (int c = t * 32; c < t * 32 + 32; ++c) { cstart[c] = run; run += ccnt[c]; }
}
__global__ void k_scatter(const int* __restrict__ lab, const int* __restrict__ cstart,
                          int* __restrict__ coff, int* __restrict__ cmember, int Bn) {
    for (int j = blockIdx.x * 256 + threadIdx.x; j < Bn; j += gridDim.x * 256) {
        int l = lab[j] & (NC - 1);
        int p = atomicAdd(&coff[l], 1);
        cmember[cstart[l] + p] = j;
    }
}

// ---------------------------------------------------------------------------
// K2: per-ANCHOR positive stats (8192 blocks -> 32 blocks/CU, fixes the 4%
// occupancy of the per-class version). Anchor row staged fp32 in LDS; each
// of 4 waves takes 1/4 of the class members; one uint4-pair (16B hi + 16B lo)
// per lane covers the full D=512 dot. Also inits minbits/poscnt.
// ---------------------------------------------------------------------------
__global__ __launch_bounds__(256) void k_posstats3(
    const unsigned short* __restrict__ fh, const unsigned short* __restrict__ fl,
    const float* __restrict__ sq, const int* __restrict__ lab,
    const int* __restrict__ cmember, const int* __restrict__ cstart,
    const int* __restrict__ ccnt,
    float* __restrict__ meanpos, int* __restrict__ poscnt,
    unsigned* __restrict__ minbits) {
    __shared__ float fi[D];
    __shared__ float wsum[4];
    int i = blockIdx.x;
    int tid = threadIdx.x, w = tid >> 6, L = tid & 63;
    int li = lab[i] & (NC - 1);
    int m = ccnt[li], st = cstart[li];

    for (int c = tid; c < D; c += 256)
        fi[c] = bf2f(fh[(size_t)i * D + c]) + bf2f(fl[(size_t)i * D + c]);
    if (tid < 4) wsum[tid] = 0.f;
    __syncthreads();

    float sqi = sq[i];
    float accw = 0.f;
    // lane L owns elements [L*8, L*8+8)
    float4 fa = *(const float4*)&fi[L * 8];
    float4 fb = *(const float4*)&fi[L * 8 + 4];
    for (int t = w; t < m; t += 4) {
        int j = cmember[st + t];
        uint4 h  = *(const uint4*)(fh + (size_t)j * D + L * 8);
        uint4 lo = *(const uint4*)(fl + (size_t)j * D + L * 8);
        float dot = 0.f;
        dot = fmaf(fa.x, __uint_as_float(h.x << 16)        + __uint_as_float(lo.x << 16),        dot);
        dot = fmaf(fa.y, __uint_as_float(h.x & 0xffff0000u) + __uint_as_float(lo.x & 0xffff0000u), dot);
        dot = fmaf(fa.z, __uint_as_float(h.y << 16)        + __uint_as_float(lo.y << 16),        dot);
        dot = fmaf(fa.w, __uint_as_float(h.y & 0xffff0000u) + __uint_as_float(lo.y & 0xffff0000u), dot);
        dot = fmaf(fb.x, __uint_as_float(h.z << 16)        + __uint_as_float(lo.z << 16),        dot);
        dot = fmaf(fb.y, __uint_as_float(h.z & 0xffff0000u) + __uint_as_float(lo.z & 0xffff0000u), dot);
        dot = fmaf(fb.z, __uint_as_float(h.w << 16)        + __uint_as_float(lo.w << 16),        dot);
        dot = fmaf(fb.w, __uint_as_float(h.w & 0xffff0000u) + __uint_as_float(lo.w & 0xffff0000u), dot);
        #pragma unroll
        for (int off = 32; off; off >>= 1) dot += __shfl_down(dot, off, 64);
        if (L == 0) {
            float d2 = sqi + sq[j] - 2.0f * dot;
            accw += (d2 > 0.f) ? sqrtf(d2) : 0.f;
        }
    }
    if (L == 0) wsum[w] = accw;
    __syncthreads();
    if (tid == 0) {
        meanpos[i] = (wsum[0] + wsum[1] + wsum[2] + wsum[3]) / (float)m;
        poscnt[i] = m;
        minbits[i] = INF_BITS;
    }
}

// ---------------------------------------------------------------------------
// K3: bf16-split MFMA GEMM (hi*hi + hi*lo + lo*hi) + fused semi-hard min.
// SYMMETRIC: only upper-triangular blocks (j0 >= i0) run; each updates
// row-anchors (rows, threshold meanpos_row) AND col-anchors (cols, threshold
// meanpos_col). atomicMin is idempotent so overlap is harmless; diagonal
// blocks skip the redundant col pass.
// ---------------------------------------------------------------------------
__global__ __launch_bounds__(256, 2) void k_minsh_mfma(
    const unsigned short* __restrict__ fh, const unsigned short* __restrict__ fl,
    const float* __restrict__ sq, const int* __restrict__ lab,
    const float* __restrict__ meanpos, unsigned* __restrict__ minbits)
{
    if (blockIdx.x < blockIdx.y) return;   // lower triangle: mirror handled by col pass

    // LA[0]=A_hi, LA[1]=A_lo, LA[2]=B_hi, LA[3]=B_lo; each 128 rows x 32 bf16
    __shared__ unsigned short LA[4][4096];
    __shared__ float s_mposr[128], s_mposc[128], s_sqr[128], s_sqc[128];
    __shared__ int s_labr[128], s_labc[128];

    const int i0 = blockIdx.y * 128, j0 = blockIdx.x * 128;
    const bool diag = (i0 == j0);
    const int tid = threadIdx.x;
    const int w = tid >> 6, L = tid & 63;

    if (tid < 128) {
        s_mposr[tid] = meanpos[i0 + tid];
        s_sqr[tid]   = sq[i0 + tid];
        s_labr[tid]  = lab[i0 + tid];
    } else {
        int t = tid - 128;
        s_mposc[t] = meanpos[j0 + t];
        s_sqc[t]   = sq[j0 + t];
        s_labc[t]  = lab[j0 + t];
    }

    const unsigned short* msrc = (w & 1) ? fl : fh;   // wave stages one matrix
    const int rbase = (w < 2) ? i0 : j0;
    unsigned short* mylds = &LA[w][0];
    const int srow = L >> 2;       // row offset within a 16-row group
    const int sseg = L & 3;        // LDS slot seg for this lane

    float4v acc[4][4];
    #pragma unroll
    for (int a = 0; a < 4; ++a) {
        #pragma unroll
        for (int b = 0; b < 4; ++b) acc[a][b] = (float4v){0.f, 0.f, 0.f, 0.f};
    }

    const int rw = (w >> 1) * 64, cw = (w & 1) * 64;
    const int lm = L & 15, ls = L >> 4;

    for (int k0 = 0; k0 < D; k0 += 32) {
        __syncthreads();
        #pragma unroll
        for (int it = 0; it < 8; ++it) {
            int r = it * 16 + srow;
            int seg = sseg ^ ((r >> 1) & 3);     // source seg for this LDS slot
            const unsigned short* g = msrc + (size_t)(rbase + r) * D + k0 + seg * 8;
            gl16(g, mylds + it * 512);           // lds ptr wave-uniform; +L*16B implied
        }
        __syncthreads();

        short8 ah[4], al[4];
        #pragma unroll
        for (int mi = 0; mi < 4; ++mi) {
            int r = rw + mi * 16 + lm;
            int slot = r * 4 + (ls ^ ((r >> 1) & 3));
            ah[mi] = *(const short8*)&LA[0][slot * 8];
            al[mi] = *(const short8*)&LA[1][slot * 8];
        }
        #pragma unroll
        for (int ni = 0; ni < 4; ++ni) {
            int c = cw + ni * 16 + lm;
            int slot = c * 4 + (ls ^ ((c >> 1) & 3));
            short8 bh = *(const short8*)&LA[2][slot * 8];
            short8 bl = *(const short8*)&LA[3][slot * 8];
            #pragma unroll
            for (int mi = 0; mi < 4; ++mi) {
                acc[mi][ni] = __builtin_amdgcn_mfma_f32_16x16x32_bf16(ah[mi], bh, acc[mi][ni], 0, 0, 0);
                acc[mi][ni] = __builtin_amdgcn_mfma_f32_16x16x32_bf16(ah[mi], bl, acc[mi][ni], 0, 0, 0);
                acc[mi][ni] = __builtin_amdgcn_mfma_f32_16x16x32_bf16(al[mi], bh, acc[mi][ni], 0, 0, 0);
            }
        }
    }

    // Epilogue. C/D layout: col = cw + ni*16 + lm, row = rw + mi*16 + ls*4 + v.
    float vminc[4];   // per-ni column partial min (this lane's 4 columns)
    #pragma unroll
    for (int ni = 0; ni < 4; ++ni) vminc[ni] = __uint_as_float(INF_BITS);

    #pragma unroll
    for (int mi = 0; mi < 4; ++mi) {
        #pragma unroll
        for (int v = 0; v < 4; ++v) {
            int rl = rw + mi * 16 + ls * 4 + v;
            float mpR = s_mposr[rl];
            float sr  = s_sqr[rl];
            int   li  = s_labr[rl];
            float vminr = __uint_as_float(INF_BITS);
            #pragma unroll
            for (int ni = 0; ni < 4; ++ni) {
                int cl = cw + ni * 16 + lm;
                float d2 = sr + s_sqc[cl] - 2.0f * acc[mi][ni][v];
                float dist = (d2 > 0.f) ? sqrtf(d2) : 0.f;
                bool neq = (li != s_labc[cl]);
                vminr = (neq && dist > mpR)          ? fminf(vminr, dist) : vminr;
                vminc[ni] = (neq && dist > s_mposc[cl]) ? fminf(vminc[ni], dist) : vminc[ni];
            }
            #pragma unroll
            for (int off = 8; off; off >>= 1)
                vminr = fminf(vminr, __shfl_xor(vminr, off, 64));
            if (lm == 0 && __float_as_uint(vminr) != INF_BITS)
                atomicMin(&minbits[i0 + rl], __float_as_uint(vminr));
        }
    }
    if (!diag) {
        #pragma unroll
        for (int ni = 0; ni < 4; ++ni) {
            float vc = vminc[ni];
            vc = fminf(vc, __shfl_xor(vc, 16, 64));   // reduce across ls bits
            vc = fminf(vc, __shfl_xor(vc, 32, 64));
            if (ls == 0 && __float_as_uint(vc) != INF_BITS)
                atomicMin(&minbits[j0 + cw + ni * 16 + lm], __float_as_uint(vc));
        }
    }
}

// ---------------------------------------------------------------------------
// K4: final scalar reduction.
// ---------------------------------------------------------------------------
__global__ void k_finish(const float* __restrict__ meanpos, const int* __restrict__ poscnt,
                         const unsigned* __restrict__ minbits, float* __restrict__ out, int Bn) {
    float lsum = 0.f; int lcnt = 0;
    for (int i = threadIdx.x; i < Bn; i += blockDim.x) {
        int pc = poscnt[i];
        bool valid = (pc > 1) && (pc < Bn);
        unsigned mb = minbits[i];
        if (valid && mb != INF_BITS) {
            float v = meanpos[i] - __uint_as_float(mb) + MARGIN;
            lsum += (v > 0.f) ? v : 0.f;
            lcnt += 1;
        }
    }
    __shared__ float ssum[4]; __shared__ int scnt[4];
    int lane = threadIdx.x & 63, wid = threadIdx.x >> 6;
    #pragma unroll
    for (int off = 32; off; off >>= 1) {
        lsum += __shfl_down(lsum, off, 64);
        lcnt += __shfl_down(lcnt, off, 64);
    }
    if (lane == 0) { ssum[wid] = lsum; scnt[wid] = lcnt; }
    __syncthreads();
    if (threadIdx.x == 0) {
        float s = ssum[0] + ssum[1] + ssum[2] + ssum[3];
        int   c = scnt[0] + scnt[1] + scnt[2] + scnt[3];
        out[0] = (c > 0) ? s / (float)c : 0.f;
    }
}

// ---------------------------------------------------------------------------
extern "C" void kernel_launch(void* const* d_in, const int* in_sizes, int n_in,
                              void* d_out, int out_size, void* d_ws, size_t ws_size,
                              hipStream_t stream) {
    const float* x = (const float*)d_in[0];
    const int* lab = (const int*)d_in[1];
    int Bn = in_sizes[1];                 // 8192; D fixed at 512

    size_t nd = (size_t)Bn * D;
    unsigned short* fh = (unsigned short*)d_ws;
    unsigned short* fl = fh + nd;
    float* sq       = (float*)(fl + nd);
    float* meanpos  = sq + Bn;
    int* poscnt     = (int*)(meanpos + Bn);
    unsigned* minbits = (unsigned*)(poscnt + Bn);
    int* ccnt    = (int*)(minbits + Bn);
    int* cstart  = ccnt + NC;
    int* coff    = cstart + NC;
    int* cmember = coff + NC;

    k_normalize<<<Bn, 256, 0, stream>>>(x, fh, fl, sq);
    k_zero<<<NC / 256, 256, 0, stream>>>(ccnt, coff);
    k_count<<<32, 256, 0, stream>>>(lab, ccnt, Bn);
    k_scan<<<1, 256, 0, stream>>>(ccnt, cstart);
    k_scatter<<<32, 256, 0, stream>>>(lab, cstart, coff, cmember, Bn);
    k_posstats3<<<Bn, 256, 0, stream>>>(fh, fl, sq, lab, cmember, cstart, ccnt,
                                        meanpos, poscnt, minbits);
    dim3 grid(Bn / 128, Bn / 128);
    k_minsh_mfma<<<grid, 256, 0, stream>>>(fh, fl, sq, lab, meanpos, minbits);
    k_finish<<<1, 256, 0, stream>>>(meanpos, poscnt, minbits, (float*)d_out, Bn);
}

// Round 4
// 204.540 us; speedup vs baseline: 6.6741x; 1.8583x over previous
//
#include <hip/hip_runtime.h>
#include <math.h>

#define EPS_N 1e-12f
#define MARGIN 0.3f
#define INF_BITS 0x7f800000u
#define NC 8192      // class-id space (labels here are 0..127)
#define D 512

typedef __attribute__((ext_vector_type(8))) short short8;   // 8 bf16 = 4 VGPRs
typedef __attribute__((ext_vector_type(4))) float float4v;  // MFMA 16x16 accum

__device__ __forceinline__ unsigned short f2bf(float f) {   // RNE bf16
    unsigned u = __float_as_uint(f);
    u += 0x7fff + ((u >> 16) & 1);
    return (unsigned short)(u >> 16);
}
__device__ __forceinline__ float bf2f(unsigned short h) {
    return __uint_as_float(((unsigned)h) << 16);
}
__device__ __forceinline__ void gl16(const void* g, void* l) {
    // 16B async global->LDS; global addr per-lane, LDS dest = uniform base + lane*16
    __builtin_amdgcn_global_load_lds((const __attribute__((address_space(1))) void*)g,
                                     (__attribute__((address_space(3))) void*)l, 16, 0, 0);
}

// ---------------------------------------------------------------------------
// K1: normalize rows; emit bf16 (hi-only: rel err 2^-9, loss err ~3e-4 vs
// 6e-3 threshold) + fp32 sq = ||fn||^2.
// ---------------------------------------------------------------------------
__global__ void k_normalize(const float* __restrict__ x, unsigned short* __restrict__ fh,
                            float* __restrict__ sq) {
    int row = blockIdx.x;
    const float* xr = x + (size_t)row * D;
    float ss = 0.f;
    for (int c = threadIdx.x; c < D; c += 256) { float v = xr[c]; ss = fmaf(v, v, ss); }
    int lane = threadIdx.x & 63, wid = threadIdx.x >> 6;
    #pragma unroll
    for (int off = 32; off; off >>= 1) ss += __shfl_down(ss, off, 64);
    __shared__ float warp_s[4];
    __shared__ float inv_s;
    if (lane == 0) warp_s[wid] = ss;
    __syncthreads();
    if (threadIdx.x == 0) {
        float t = warp_s[0] + warp_s[1] + warp_s[2] + warp_s[3];
        float inv = 1.0f / fmaxf(sqrtf(t), EPS_N);
        inv_s = inv;
        sq[row] = t * inv * inv;
    }
    __syncthreads();
    float inv = inv_s;
    for (int c = threadIdx.x; c < D; c += 256) fh[(size_t)row * D + c] = f2bf(xr[c] * inv);
}

// ---------------------------------------------------------------------------
// Class bucketing: zero -> count -> scan -> scatter
// ---------------------------------------------------------------------------
__global__ void k_zero(int* __restrict__ ccnt, int* __restrict__ coff) {
    int i = blockIdx.x * 256 + threadIdx.x;
    if (i < NC) { ccnt[i] = 0; coff[i] = 0; }
}
__global__ void k_count(const int* __restrict__ lab, int* __restrict__ ccnt, int Bn) {
    for (int j = blockIdx.x * 256 + threadIdx.x; j < Bn; j += gridDim.x * 256)
        atomicAdd(&ccnt[lab[j] & (NC - 1)], 1);
}
__global__ void k_scan(const int* __restrict__ ccnt, int* __restrict__ cstart) {
    __shared__ int part[256];
    int t = threadIdx.x;
    int s = 0;
    for (int c = t * 32; c < t * 32 + 32; ++c) s += ccnt[c];
    part[t] = s;
    __syncthreads();
    if (t == 0) { int run = 0; for (int q = 0; q < 256; ++q) { int v = part[q]; part[q] = run; run += v; } }
    __syncthreads();
    int run = part[t];
    for (int c = t * 32; c < t * 32 + 32; ++c) { cstart[c] = run; run += ccnt[c]; }
}
__global__ void k_scatter(const int* __restrict__ lab, const int* __restrict__ cstart,
                          int* __restrict__ coff, int* __restrict__ cmember, int Bn) {
    for (int j = blockIdx.x * 256 + threadIdx.x; j < Bn; j += gridDim.x * 256) {
        int l = lab[j] & (NC - 1);
        int p = atomicAdd(&coff[l], 1);
        cmember[cstart[l] + p] = j;
    }
}

// ---------------------------------------------------------------------------
// K2: per-CLASS positive stats via MFMA Gram matrix. One block per class:
// gather-stage m<=128 member rows (K-chunks of 32) once, compute m x m dots
// with the proven XOR-swizzled layout, row-sum dists in LDS. Reads each
// class's data ONCE (vs 64x in the per-anchor version: 1 GB -> 16 MB).
// Diagonal masked explicitly (hi-only bf16 would give dist(i,i)~0.014).
// ---------------------------------------------------------------------------
__global__ __launch_bounds__(256) void k_posclass(
    const unsigned short* __restrict__ fh, const float* __restrict__ sq,
    const int* __restrict__ cmember, const int* __restrict__ cstart,
    const int* __restrict__ ccnt,
    float* __restrict__ meanpos, int* __restrict__ poscnt,
    unsigned* __restrict__ minbits) {
    int c = blockIdx.x;
    int m = ccnt[c];
    if (m == 0) return;
    int st = cstart[c];
    int tid = threadIdx.x, w = tid >> 6, L = tid & 63;

    if (m <= 128) {
        __shared__ unsigned short S[128 * 32];   // 8 KB K-chunk, swizzled
        __shared__ int cml[128];
        __shared__ float sql[128], rs[128];
        for (int t = tid; t < 128; t += 256) {
            int g = cmember[st + min(t, m - 1)];
            cml[t] = g;
            sql[t] = sq[g];
            rs[t] = 0.f;
        }
        __syncthreads();
        // staging: wave w owns rows [w*32, w*32+32); lane L rows r0, r0+16
        int r0 = w * 32 + (L >> 2), r1 = r0 + 16;
        const unsigned short* g0 = fh + (size_t)cml[r0] * D;
        const unsigned short* g1 = fh + (size_t)cml[r1] * D;
        int sseg = L & 3;
        int seg0 = sseg ^ ((r0 >> 1) & 3), seg1 = sseg ^ ((r1 >> 1) & 3);
        unsigned short* d0 = &S[(size_t)(w * 32) * 32];
        unsigned short* d1 = &S[(size_t)(w * 32 + 16) * 32];

        const int rw = (w >> 1) * 64, cw = (w & 1) * 64, lm = L & 15, ls = L >> 4;
        float4v acc[4][4];
        #pragma unroll
        for (int a = 0; a < 4; ++a)
            #pragma unroll
            for (int b = 0; b < 4; ++b) acc[a][b] = (float4v){0.f, 0.f, 0.f, 0.f};

        for (int k0 = 0; k0 < D; k0 += 32) {
            __syncthreads();
            gl16(g0 + k0 + seg0 * 8, d0);
            gl16(g1 + k0 + seg1 * 8, d1);
            __syncthreads();
            short8 ah[4];
            #pragma unroll
            for (int mi = 0; mi < 4; ++mi) {
                int r = rw + mi * 16 + lm;
                int slot = r * 4 + (ls ^ ((r >> 1) & 3));
                ah[mi] = *(const short8*)&S[slot * 8];
            }
            #pragma unroll
            for (int ni = 0; ni < 4; ++ni) {
                int cc = cw + ni * 16 + lm;
                int slot = cc * 4 + (ls ^ ((cc >> 1) & 3));
                short8 bh = *(const short8*)&S[slot * 8];
                #pragma unroll
                for (int mi = 0; mi < 4; ++mi)
                    acc[mi][ni] = __builtin_amdgcn_mfma_f32_16x16x32_bf16(ah[mi], bh, acc[mi][ni], 0, 0, 0);
            }
        }
        __syncthreads();
        // epilogue: row-sum of masked dists. C/D: row = rw+mi*16+ls*4+v, col = cw+ni*16+lm
        #pragma unroll
        for (int mi = 0; mi < 4; ++mi) {
            #pragma unroll
            for (int v = 0; v < 4; ++v) {
                int rl = rw + mi * 16 + ls * 4 + v;
                float sr = sql[rl];
                float sum = 0.f;
                #pragma unroll
                for (int ni = 0; ni < 4; ++ni) {
                    int cl = cw + ni * 16 + lm;
                    float d2 = sr + sql[cl] - 2.0f * acc[mi][ni][v];
                    float dd = (d2 > 0.f) ? sqrtf(d2) : 0.f;
                    sum += ((cl < m) && (cl != rl)) ? dd : 0.f;
                }
                #pragma unroll
                for (int off = 8; off; off >>= 1) sum += __shfl_xor(sum, off, 64);
                if (lm == 0 && rl < m) atomicAdd(&rs[rl], sum);
            }
        }
        __syncthreads();
        for (int t = tid; t < m; t += 256) {
            int g = cml[t];
            meanpos[g] = rs[t] / (float)m;
            poscnt[g] = m;
            minbits[g] = INF_BITS;
        }
    } else {
        // fallback for pathological class sizes (not hit with Poisson(64) data)
        for (int t = tid; t < m; t += 256) meanpos[cmember[st + t]] = 0.f;
        __syncthreads();
        for (size_t p = tid; p < (size_t)m * m; p += 256) {
            int a = (int)(p / m), b = (int)(p % m);
            if (a == b) continue;
            int ga = cmember[st + a], gb = cmember[st + b];
            float dotv = 0.f;
            for (int k = 0; k < D; ++k)
                dotv = fmaf(bf2f(fh[(size_t)ga * D + k]), bf2f(fh[(size_t)gb * D + k]), dotv);
            float d2 = sq[ga] + sq[gb] - 2.0f * dotv;
            atomicAdd(&meanpos[ga], (d2 > 0.f) ? sqrtf(d2) : 0.f);
        }
        __syncthreads();
        for (int t = tid; t < m; t += 256) {
            int g = cmember[st + t];
            meanpos[g] /= (float)m;
            poscnt[g] = m;
            minbits[g] = INF_BITS;
        }
    }
}

// ---------------------------------------------------------------------------
// K3: hi-only bf16 MFMA GEMM + fused semi-hard min, symmetric (triangular 1D
// grid of 2080 blocks, no dead launches). BK=64: halves barrier count vs R3;
// LDS 32 KB + meta -> 4 blocks/CU. Each block updates row-anchors AND
// col-anchors (atomicMin is idempotent; diagonal skips the col pass).
// ---------------------------------------------------------------------------
#define BKG 64

__global__ __launch_bounds__(256, 4) void k_minsh_mfma(
    const unsigned short* __restrict__ fh, const float* __restrict__ sq,
    const int* __restrict__ lab, const float* __restrict__ meanpos,
    unsigned* __restrict__ minbits)
{
    // triangular decode: block t -> (rq, cq), cq <= rq
    int t = blockIdx.x;
    int rq = (int)((sqrtf(8.0f * (float)t + 1.0f) - 1.0f) * 0.5f);
    while ((rq + 1) * (rq + 2) / 2 <= t) ++rq;
    while (rq * (rq + 1) / 2 > t) --rq;
    int cq = t - rq * (rq + 1) / 2;
    const int i0 = cq * 128, j0 = rq * 128;
    const bool diag = (i0 == j0);

    __shared__ unsigned short LA[2][128 * BKG];   // [0]=A rows, [1]=B rows; 32 KB
    __shared__ float s_mposr[128], s_mposc[128], s_sqr[128], s_sqc[128];
    __shared__ int s_labr[128], s_labc[128];

    const int tid = threadIdx.x;
    const int w = tid >> 6, L = tid & 63;

    if (tid < 128) {
        s_mposr[tid] = meanpos[i0 + tid];
        s_sqr[tid]   = sq[i0 + tid];
        s_labr[tid]  = lab[i0 + tid];
    } else {
        int q = tid - 128;
        s_mposc[q] = meanpos[j0 + q];
        s_sqc[q]   = sq[j0 + q];
        s_labc[q]  = lab[j0 + q];
    }

    // staging roles: waves 0,1 -> A halves; waves 2,3 -> B halves
    const unsigned short* msrc = fh + (size_t)((w < 2) ? i0 : j0) * D;
    unsigned short* mylds = &LA[(w < 2) ? 0 : 1][(w & 1) * 64 * BKG];
    const int srow = L >> 3;   // 0..7
    const int sseg = L & 7;    // 0..7 (16B segs of a 128B row-chunk)

    float4v acc[4][4];
    #pragma unroll
    for (int a = 0; a < 4; ++a)
        #pragma unroll
        for (int b = 0; b < 4; ++b) acc[a][b] = (float4v){0.f, 0.f, 0.f, 0.f};

    const int rw = (w >> 1) * 64, cw = (w & 1) * 64;
    const int lm = L & 15, ls = L >> 4;

    for (int k0 = 0; k0 < D; k0 += BKG) {
        __syncthreads();
        #pragma unroll
        for (int it = 0; it < 8; ++it) {
            int rmat = (w & 1) * 64 + it * 8 + srow;     // row within 128
            int seg = sseg ^ (rmat & 7);                 // source seg for this slot
            gl16(msrc + (size_t)rmat * D + k0 + seg * 8, mylds + it * 512);
        }
        __syncthreads();
        #pragma unroll
        for (int h = 0; h < 2; ++h) {
            short8 ah[4], bh[4];
            #pragma unroll
            for (int mi = 0; mi < 4; ++mi) {
                int r = rw + mi * 16 + lm;
                int slot = r * 8 + ((h * 4 + ls) ^ (r & 7));
                ah[mi] = *(const short8*)&LA[0][slot * 8];
            }
            #pragma unroll
            for (int ni = 0; ni < 4; ++ni) {
                int cc = cw + ni * 16 + lm;
                int slot = cc * 8 + ((h * 4 + ls) ^ (cc & 7));
                bh[ni] = *(const short8*)&LA[1][slot * 8];
            }
            #pragma unroll
            for (int ni = 0; ni < 4; ++ni)
                #pragma unroll
                for (int mi = 0; mi < 4; ++mi)
                    acc[mi][ni] = __builtin_amdgcn_mfma_f32_16x16x32_bf16(ah[mi], bh[ni], acc[mi][ni], 0, 0, 0);
        }
    }

    // Epilogue: row pass + col pass. C/D: row = rw+mi*16+ls*4+v, col = cw+ni*16+lm
    float vminc[4];
    #pragma unroll
    for (int ni = 0; ni < 4; ++ni) vminc[ni] = __uint_as_float(INF_BITS);

    #pragma unroll
    for (int mi = 0; mi < 4; ++mi) {
        #pragma unroll
        for (int v = 0; v < 4; ++v) {
            int rl = rw + mi * 16 + ls * 4 + v;
            float mpR = s_mposr[rl];
            float sr  = s_sqr[rl];
            int   li  = s_labr[rl];
            float vminr = __uint_as_float(INF_BITS);
            #pragma unroll
            for (int ni = 0; ni < 4; ++ni) {
                int cl = cw + ni * 16 + lm;
                float d2 = sr + s_sqc[cl] - 2.0f * acc[mi][ni][v];
                float dist = (d2 > 0.f) ? sqrtf(d2) : 0.f;
                bool neq = (li != s_labc[cl]);
                vminr = (neq && dist > mpR)             ? fminf(vminr, dist) : vminr;
                vminc[ni] = (neq && dist > s_mposc[cl]) ? fminf(vminc[ni], dist) : vminc[ni];
            }
            #pragma unroll
            for (int off = 8; off; off >>= 1)
                vminr = fminf(vminr, __shfl_xor(vminr, off, 64));
            if (lm == 0 && __float_as_uint(vminr) != INF_BITS)
                atomicMin(&minbits[i0 + rl], __float_as_uint(vminr));
        }
    }
    if (!diag) {
        #pragma unroll
        for (int ni = 0; ni < 4; ++ni) {
            float vc = vminc[ni];
            vc = fminf(vc, __shfl_xor(vc, 16, 64));
            vc = fminf(vc, __shfl_xor(vc, 32, 64));
            if (ls == 0 && __float_as_uint(vc) != INF_BITS)
                atomicMin(&minbits[j0 + cw + ni * 16 + lm], __float_as_uint(vc));
        }
    }
}

// ---------------------------------------------------------------------------
// K4: final scalar reduction.
// ---------------------------------------------------------------------------
__global__ void k_finish(const float* __restrict__ meanpos, const int* __restrict__ poscnt,
                         const unsigned* __restrict__ minbits, float* __restrict__ out, int Bn) {
    float lsum = 0.f; int lcnt = 0;
    for (int i = threadIdx.x; i < Bn; i += blockDim.x) {
        int pc = poscnt[i];
        bool valid = (pc > 1) && (pc < Bn);
        unsigned mb = minbits[i];
        if (valid && mb != INF_BITS) {
            float v = meanpos[i] - __uint_as_float(mb) + MARGIN;
            lsum += (v > 0.f) ? v : 0.f;
            lcnt += 1;
        }
    }
    __shared__ float ssum[4]; __shared__ int scnt[4];
    int lane = threadIdx.x & 63, wid = threadIdx.x >> 6;
    #pragma unroll
    for (int off = 32; off; off >>= 1) {
        lsum += __shfl_down(lsum, off, 64);
        lcnt += __shfl_down(lcnt, off, 64);
    }
    if (lane == 0) { ssum[wid] = lsum; scnt[wid] = lcnt; }
    __syncthreads();
    if (threadIdx.x == 0) {
        float s = ssum[0] + ssum[1] + ssum[2] + ssum[3];
        int   c = scnt[0] + scnt[1] + scnt[2] + scnt[3];
        out[0] = (c > 0) ? s / (float)c : 0.f;
    }
}

// ---------------------------------------------------------------------------
extern "C" void kernel_launch(void* const* d_in, const int* in_sizes, int n_in,
                              void* d_out, int out_size, void* d_ws, size_t ws_size,
                              hipStream_t stream) {
    const float* x = (const float*)d_in[0];
    const int* lab = (const int*)d_in[1];
    int Bn = in_sizes[1];                 // 8192; D fixed at 512

    size_t nd = (size_t)Bn * D;
    unsigned short* fh = (unsigned short*)d_ws;
    float* sq       = (float*)(fh + nd);
    float* meanpos  = sq + Bn;
    int* poscnt     = (int*)(meanpos + Bn);
    unsigned* minbits = (unsigned*)(poscnt + Bn);
    int* ccnt    = (int*)(minbits + Bn);
    int* cstart  = ccnt + NC;
    int* coff    = cstart + NC;
    int* cmember = coff + NC;

    k_normalize<<<Bn, 256, 0, stream>>>(x, fh, sq);
    k_zero<<<NC / 256, 256, 0, stream>>>(ccnt, coff);
    k_count<<<32, 256, 0, stream>>>(lab, ccnt, Bn);
    k_scan<<<1, 256, 0, stream>>>(ccnt, cstart);
    k_scatter<<<32, 256, 0, stream>>>(lab, cstart, coff, cmember, Bn);
    k_posclass<<<NC, 256, 0, stream>>>(fh, sq, cmember, cstart, ccnt,
                                       meanpos, poscnt, minbits);
    int nb = Bn / 128;
    int T = nb * (nb + 1) / 2;
    k_minsh_mfma<<<T, 256, 0, stream>>>(fh, sq, lab, meanpos, minbits);
    k_finish<<<1, 256, 0, stream>>>(meanpos, poscnt, minbits, (float*)d_out, Bn);
}

// Round 5
// 182.177 us; speedup vs baseline: 7.4933x; 1.1228x over previous
//
#include <hip/hip_runtime.h>
#include <math.h>

#define EPS_N 1e-12f
#define MARGIN 0.3f
#define INF_BITS 0x7f800000u
#define NCLS 128     // label space (randint(0,128))
#define D 512
#define PADR 256     // padded rows after fh so banded staging can over-read safely

typedef __attribute__((ext_vector_type(8))) short short8;   // 8 bf16 = 4 VGPRs
typedef __attribute__((ext_vector_type(4))) float float4v;  // MFMA 16x16 accum

__device__ __forceinline__ unsigned short f2bf(float f) {   // RNE bf16
    unsigned u = __float_as_uint(f);
    u += 0x7fff + ((u >> 16) & 1);
    return (unsigned short)(u >> 16);
}
__device__ __forceinline__ void gl16(const void* g, void* l) {
    // 16B async global->LDS; global addr per-lane, LDS dest = uniform base + lane*16
    __builtin_amdgcn_global_load_lds((const __attribute__((address_space(1))) void*)g,
                                     (__attribute__((address_space(3))) void*)l, 16, 0, 0);
}

// ---------------------------------------------------------------------------
// K0: one-block bucketing. labels -> pos[i] (orig row -> permuted slot),
// labp[p] (label of permuted slot), cstart/ccnt per class. Replaces 4 kernels.
// ---------------------------------------------------------------------------
__global__ __launch_bounds__(1024) void k_bucket(const int* __restrict__ lab, int Bn,
        int* __restrict__ pos, int* __restrict__ labp,
        int* __restrict__ cstart_g, int* __restrict__ ccnt_g) {
    __shared__ int cnt[NCLS], off[NCLS], sa[NCLS], sb[NCLS];
    int tid = threadIdx.x;
    if (tid < NCLS) cnt[tid] = 0;
    __syncthreads();
    for (int i = tid; i < Bn; i += 1024) atomicAdd(&cnt[lab[i] & (NCLS - 1)], 1);
    __syncthreads();
    if (tid < NCLS) sa[tid] = cnt[tid];
    __syncthreads();
    int* src = sa; int* dst = sb;
    for (int ofs = 1; ofs < NCLS; ofs <<= 1) {          // Hillis-Steele inclusive scan
        if (tid < NCLS) dst[tid] = src[tid] + ((tid >= ofs) ? src[tid - ofs] : 0);
        __syncthreads();
        int* t = src; src = dst; dst = t;
    }
    if (tid < NCLS) {
        int ex = src[tid] - cnt[tid];                   // exclusive
        off[tid] = ex;
        cstart_g[tid] = ex;
        ccnt_g[tid] = cnt[tid];
    }
    __syncthreads();
    for (int i = tid; i < Bn; i += 1024) {
        int l = lab[i] & (NCLS - 1);
        int p = atomicAdd(&off[l], 1);
        pos[i] = p;
        labp[p] = l;
    }
}

// ---------------------------------------------------------------------------
// K1: normalize row i, write bf16 (hi-only) to PERMUTED slot pos[i] + sqp.
// ---------------------------------------------------------------------------
__global__ void k_normalize(const float* __restrict__ x, const int* __restrict__ pos,
                            unsigned short* __restrict__ fh, float* __restrict__ sqp) {
    int row = blockIdx.x;
    const float* xr = x + (size_t)row * D;
    float ss = 0.f;
    for (int c = threadIdx.x; c < D; c += 256) { float v = xr[c]; ss = fmaf(v, v, ss); }
    int lane = threadIdx.x & 63, wid = threadIdx.x >> 6;
    #pragma unroll
    for (int off = 32; off; off >>= 1) ss += __shfl_down(ss, off, 64);
    __shared__ float warp_s[4];
    __shared__ float inv_s;
    if (lane == 0) warp_s[wid] = ss;
    __syncthreads();
    int prow = pos[row];
    if (threadIdx.x == 0) {
        float t = warp_s[0] + warp_s[1] + warp_s[2] + warp_s[3];
        float inv = 1.0f / fmaxf(sqrtf(t), EPS_N);
        inv_s = inv;
        sqp[prow] = t * inv * inv;
    }
    __syncthreads();
    float inv = inv_s;
    for (int c = threadIdx.x; c < D; c += 256) fh[(size_t)prow * D + c] = f2bf(xr[c] * inv);
}

// ---------------------------------------------------------------------------
// K2: banded positive stats. Classes are contiguous in permuted order, so all
// same-class pairs sit in a <128-wide diagonal band. One block per 32 rows
// (Bn/32 = 256 blocks -> 1/CU): MFMA Gram of 32 rows vs the contiguous
// <=256-col class window (looped if wider). Each row's whole class is inside
// this block -> LDS-only accumulation. Also inits poscnt/minbits.
// ---------------------------------------------------------------------------
__global__ __launch_bounds__(256) void k_posband(
    const unsigned short* __restrict__ fh, const float* __restrict__ sqp,
    const int* __restrict__ labp, const int* __restrict__ cstart_g,
    const int* __restrict__ ccnt_g,
    float* __restrict__ meanpos, int* __restrict__ poscnt,
    unsigned* __restrict__ minbits, int Bn)
{
    __shared__ unsigned short LAB[1152 * 8];   // 18 KB; slots 0..127 = A(32 rows), 128..1151 = B(256 cols)
    __shared__ float sqr[32], rs[32];
    __shared__ int labr[32];
    __shared__ float sqc[256];
    __shared__ int labc[256];
    __shared__ int s_c0, s_c1;

    const int r0 = blockIdx.x * 32;
    const int tid = threadIdx.x, w = tid >> 6, L = tid & 63;
    const int lm = L & 15, ls = L >> 4;

    if (tid < 32) {
        labr[tid] = labp[r0 + tid];
        sqr[tid]  = sqp[r0 + tid];
        rs[tid]   = 0.f;
    }
    __syncthreads();
    if (tid == 0) {
        s_c0 = cstart_g[labr[0]];
        s_c1 = cstart_g[labr[31]] + ccnt_g[labr[31]];
    }
    __syncthreads();
    const int c0 = s_c0, c1 = s_c1;

    for (int cc0 = c0; cc0 < c1; cc0 += 256) {   // one pass in practice (window <= ~220)
        __syncthreads();
        for (int t = tid; t < 256; t += 256) {
            int q = cc0 + t;
            if (q < Bn) { sqc[t] = sqp[q]; labc[t] = labp[q]; }
            else        { sqc[t] = 0.f;    labc[t] = -1; }
        }
        float4v acc[2][4];
        #pragma unroll
        for (int a = 0; a < 2; ++a)
            #pragma unroll
            for (int b = 0; b < 4; ++b) acc[a][b] = (float4v){0.f, 0.f, 0.f, 0.f};

        for (int k0 = 0; k0 < D; k0 += 32) {
            __syncthreads();
            #pragma unroll
            for (int it = 0; it < 5; ++it) {
                int sbase = it * 256 + w * 64;           // wave-uniform
                if (sbase < 1152) {                      // last iter: waves 2,3 idle (uniform)
                    int s = sbase + L;
                    int rch = s >> 2;                    // 0..287 row-chunk
                    int q = s & 3;
                    int grow = (rch < 32) ? (r0 + rch) : (cc0 + rch - 32);  // may over-read into PADR pad
                    int seg = q ^ ((rch >> 1) & 3);      // verified 32-wide swizzle
                    gl16(fh + (size_t)grow * D + k0 + seg * 8, &LAB[(size_t)sbase * 8]);
                }
            }
            __syncthreads();
            short8 af[2];
            #pragma unroll
            for (int rt = 0; rt < 2; ++rt) {
                int rr = rt * 16 + lm;
                int slot = rr * 4 + (ls ^ ((rr >> 1) & 3));
                af[rt] = *(const short8*)&LAB[slot * 8];
            }
            #pragma unroll
            for (int ct = 0; ct < 4; ++ct) {
                int cc = w * 64 + ct * 16 + lm;
                int slot = 128 + cc * 4 + (ls ^ ((cc >> 1) & 3));
                short8 bf = *(const short8*)&LAB[slot * 8];
                #pragma unroll
                for (int rt = 0; rt < 2; ++rt)
                    acc[rt][ct] = __builtin_amdgcn_mfma_f32_16x16x32_bf16(af[rt], bf, acc[rt][ct], 0, 0, 0);
            }
        }
        // epilogue: masked dist row-sums. C/D: row = rt*16+ls*4+v, col = w*64+ct*16+lm
        #pragma unroll
        for (int rt = 0; rt < 2; ++rt) {
            #pragma unroll
            for (int v = 0; v < 4; ++v) {
                int ri = rt * 16 + ls * 4 + v;
                int p = r0 + ri;
                int lr = labr[ri];
                float sr = sqr[ri];
                float sum = 0.f;
                #pragma unroll
                for (int ct = 0; ct < 4; ++ct) {
                    int ci = w * 64 + ct * 16 + lm;
                    int q = cc0 + ci;
                    float d2 = sr + sqc[ci] - 2.0f * acc[rt][ct][v];
                    float dd = (d2 > 0.f) ? sqrtf(d2) : 0.f;
                    sum += ((labc[ci] == lr) && (q != p)) ? dd : 0.f;
                }
                #pragma unroll
                for (int off = 8; off; off >>= 1) sum += __shfl_xor(sum, off, 64);
                if (lm == 0) atomicAdd(&rs[ri], sum);
            }
        }
    }
    __syncthreads();
    if (tid < 32) {
        int p = r0 + tid;
        int m = ccnt_g[labr[tid]];
        meanpos[p] = rs[tid] / (float)m;
        poscnt[p] = m;
        minbits[p] = INF_BITS;
    }
}

// ---------------------------------------------------------------------------
// K3: hi-only bf16 MFMA GEMM + fused semi-hard min (triangular grid, both
// row & col anchor passes). Epilogue in d2-space: dist>mp <=> d2>mp^2 and
// min commutes with sqrt -> minbits stores d2 bits; sqrt deferred to k_finish.
// ---------------------------------------------------------------------------
#define BKG 64

__global__ __launch_bounds__(256, 4) void k_minsh_mfma(
    const unsigned short* __restrict__ fh, const float* __restrict__ sqp,
    const int* __restrict__ labp, const float* __restrict__ meanpos,
    unsigned* __restrict__ minbits)
{
    int t = blockIdx.x;
    int rq = (int)((sqrtf(8.0f * (float)t + 1.0f) - 1.0f) * 0.5f);
    while ((rq + 1) * (rq + 2) / 2 <= t) ++rq;
    while (rq * (rq + 1) / 2 > t) --rq;
    int cq = t - rq * (rq + 1) / 2;
    const int i0 = cq * 128, j0 = rq * 128;
    const bool diag = (i0 == j0);

    __shared__ unsigned short LA[2][128 * BKG];   // 32 KB
    __shared__ float s_mp2r[128], s_mp2c[128], s_sqr[128], s_sqc[128];
    __shared__ int s_labr[128], s_labc[128];

    const int tid = threadIdx.x;
    const int w = tid >> 6, L = tid & 63;

    if (tid < 128) {
        float mp = meanpos[i0 + tid];
        s_mp2r[tid] = mp * mp;
        s_sqr[tid]  = sqp[i0 + tid];
        s_labr[tid] = labp[i0 + tid];
    } else {
        int q = tid - 128;
        float mp = meanpos[j0 + q];
        s_mp2c[q] = mp * mp;
        s_sqc[q]  = sqp[j0 + q];
        s_labc[q] = labp[j0 + q];
    }

    const unsigned short* msrc = fh + (size_t)((w < 2) ? i0 : j0) * D;
    unsigned short* mylds = &LA[(w < 2) ? 0 : 1][(w & 1) * 64 * BKG];
    const int srow = L >> 3;
    const int sseg = L & 7;

    float4v acc[4][4];
    #pragma unroll
    for (int a = 0; a < 4; ++a)
        #pragma unroll
        for (int b = 0; b < 4; ++b) acc[a][b] = (float4v){0.f, 0.f, 0.f, 0.f};

    const int rw = (w >> 1) * 64, cw = (w & 1) * 64;
    const int lm = L & 15, ls = L >> 4;

    for (int k0 = 0; k0 < D; k0 += BKG) {
        __syncthreads();
        #pragma unroll
        for (int it = 0; it < 8; ++it) {
            int rmat = (w & 1) * 64 + it * 8 + srow;
            int seg = sseg ^ (rmat & 7);
            gl16(msrc + (size_t)rmat * D + k0 + seg * 8, mylds + it * 512);
        }
        __syncthreads();
        #pragma unroll
        for (int h = 0; h < 2; ++h) {
            short8 ah[4], bh[4];
            #pragma unroll
            for (int mi = 0; mi < 4; ++mi) {
                int r = rw + mi * 16 + lm;
                int slot = r * 8 + ((h * 4 + ls) ^ (r & 7));
                ah[mi] = *(const short8*)&LA[0][slot * 8];
            }
            #pragma unroll
            for (int ni = 0; ni < 4; ++ni) {
                int cc = cw + ni * 16 + lm;
                int slot = cc * 8 + ((h * 4 + ls) ^ (cc & 7));
                bh[ni] = *(const short8*)&LA[1][slot * 8];
            }
            #pragma unroll
            for (int ni = 0; ni < 4; ++ni)
                #pragma unroll
                for (int mi = 0; mi < 4; ++mi)
                    acc[mi][ni] = __builtin_amdgcn_mfma_f32_16x16x32_bf16(ah[mi], bh[ni], acc[mi][ni], 0, 0, 0);
        }
    }

    // d2-space epilogue. C/D: row = rw+mi*16+ls*4+v, col = cw+ni*16+lm
    const float INFF = __uint_as_float(INF_BITS);
    float sc[4], mp2c[4];
    int lc[4];
    #pragma unroll
    for (int ni = 0; ni < 4; ++ni) {
        int cl = cw + ni * 16 + lm;
        sc[ni]   = s_sqc[cl];
        mp2c[ni] = s_mp2c[cl];
        lc[ni]   = s_labc[cl];
    }
    float vminc[4];
    #pragma unroll
    for (int ni = 0; ni < 4; ++ni) vminc[ni] = INFF;

    #pragma unroll
    for (int mi = 0; mi < 4; ++mi) {
        #pragma unroll
        for (int v = 0; v < 4; ++v) {
            int rl = rw + mi * 16 + ls * 4 + v;
            float mp2r = s_mp2r[rl];
            float sr   = s_sqr[rl];
            int   li   = s_labr[rl];
            float vminr = INFF;
            #pragma unroll
            for (int ni = 0; ni < 4; ++ni) {
                float d2 = fmaf(-2.0f, acc[mi][ni][v], sr + sc[ni]);
                bool neq = (li != lc[ni]);
                vminr     = fminf(vminr,     (neq && d2 > mp2r)     ? d2 : INFF);
                vminc[ni] = fminf(vminc[ni], (neq && d2 > mp2c[ni]) ? d2 : INFF);
            }
            #pragma unroll
            for (int off = 8; off; off >>= 1)
                vminr = fminf(vminr, __shfl_xor(vminr, off, 64));
            if (lm == 0 && __float_as_uint(vminr) != INF_BITS)
                atomicMin(&minbits[i0 + rl], __float_as_uint(vminr));
        }
    }
    if (!diag) {
        #pragma unroll
        for (int ni = 0; ni < 4; ++ni) {
            float vc = vminc[ni];
            vc = fminf(vc, __shfl_xor(vc, 16, 64));
            vc = fminf(vc, __shfl_xor(vc, 32, 64));
            if (ls == 0 && __float_as_uint(vc) != INF_BITS)
                atomicMin(&minbits[j0 + cw + ni * 16 + lm], __float_as_uint(vc));
        }
    }
}

// ---------------------------------------------------------------------------
// K4: final reduction. minbits holds d2 -> sqrt here.
// ---------------------------------------------------------------------------
__global__ void k_finish(const float* __restrict__ meanpos, const int* __restrict__ poscnt,
                         const unsigned* __restrict__ minbits, float* __restrict__ out, int Bn) {
    float lsum = 0.f; int lcnt = 0;
    for (int i = threadIdx.x; i < Bn; i += blockDim.x) {
        int pc = poscnt[i];
        bool valid = (pc > 1) && (pc < Bn);
        unsigned mb = minbits[i];
        if (valid && mb != INF_BITS) {
            float v = meanpos[i] - sqrtf(__uint_as_float(mb)) + MARGIN;
            lsum += (v > 0.f) ? v : 0.f;
            lcnt += 1;
        }
    }
    __shared__ float ssum[4]; __shared__ int scnt[4];
    int lane = threadIdx.x & 63, wid = threadIdx.x >> 6;
    #pragma unroll
    for (int off = 32; off; off >>= 1) {
        lsum += __shfl_down(lsum, off, 64);
        lcnt += __shfl_down(lcnt, off, 64);
    }
    if (lane == 0) { ssum[wid] = lsum; scnt[wid] = lcnt; }
    __syncthreads();
    if (threadIdx.x == 0) {
        float s = ssum[0] + ssum[1] + ssum[2] + ssum[3];
        int   c = scnt[0] + scnt[1] + scnt[2] + scnt[3];
        out[0] = (c > 0) ? s / (float)c : 0.f;
    }
}

// ---------------------------------------------------------------------------
extern "C" void kernel_launch(void* const* d_in, const int* in_sizes, int n_in,
                              void* d_out, int out_size, void* d_ws, size_t ws_size,
                              hipStream_t stream) {
    const float* x = (const float*)d_in[0];
    const int* lab = (const int*)d_in[1];
    int Bn = in_sizes[1];                 // 8192; D fixed at 512

    size_t nd = (size_t)(Bn + PADR) * D;  // padded for banded over-read
    unsigned short* fh = (unsigned short*)d_ws;
    float* sqp      = (float*)(fh + nd);
    float* meanpos  = sqp + Bn;
    int* poscnt     = (int*)(meanpos + Bn);
    unsigned* minbits = (unsigned*)(poscnt + Bn);
    int* pos        = (int*)(minbits + Bn);
    int* labp       = pos + Bn;
    int* cstart_g   = labp + Bn;
    int* ccnt_g     = cstart_g + NCLS;

    k_bucket<<<1, 1024, 0, stream>>>(lab, Bn, pos, labp, cstart_g, ccnt_g);
    k_normalize<<<Bn, 256, 0, stream>>>(x, pos, fh, sqp);
    k_posband<<<Bn / 32, 256, 0, stream>>>(fh, sqp, labp, cstart_g, ccnt_g,
                                           meanpos, poscnt, minbits, Bn);
    int nb = Bn / 128;
    int T = nb * (nb + 1) / 2;
    k_minsh_mfma<<<T, 256, 0, stream>>>(fh, sqp, labp, meanpos, minbits);
    k_finish<<<1, 256, 0, stream>>>(meanpos, poscnt, minbits, (float*)d_out, Bn);
}